// Round 5
// baseline (9335.829 us; speedup 1.0000x reference)
//
#include <hip/hip_runtime.h>
#include <hip/hip_bf16.h>
#include <math.h>
#include <stdint.h>

using bf16 = __hip_bfloat16;
typedef __attribute__((ext_vector_type(8))) short short8;   // 8 bf16 (MFMA A/B frag)
typedef __attribute__((ext_vector_type(4))) float floatx4;  // MFMA C/D frag (f32)
typedef __attribute__((ext_vector_type(4))) int int4v;      // i8 K=64 frag / i32 acc

typedef const __attribute__((address_space(1))) void* gptr_t;
typedef __attribute__((address_space(3))) void* lptr_t;

__device__ __forceinline__ void load_lds16(const void* g, void* l) {
    __builtin_amdgcn_global_load_lds((gptr_t)(uintptr_t)g, (lptr_t)(uintptr_t)l, 16, 0, 0);
}

// tanh(x) = 1 - 2/(exp(2x)+1)
__device__ __forceinline__ float fast_tanh(float x) {
    float e = __expf(2.f * x);
    return 1.f - 2.f / (e + 1.f);
}

// ===========================================================================
// Row-resident persistent kernel, ZERO grid barriers (R4 post-mortem: the
// grid barrier's device-scope fences force L2 writeback+invalidate -> 5.9 GB
// of manufactured traffic at 950 GB/s = the whole 6.2 ms). The RK4 dataflow
// is row-local in batch: x0[m]->x1[m]->x2[m]->k[m]->h[m]->x0[m]. So each of
// 256 blocks owns 32 rows through ALL 40 evals; the only shared data is the
// read-only weights (3 MB, stays hot in every XCD L2 since nothing ever
// invalidates it). No inter-block communication at all => no barrier, no
// fence, no deadlock risk, caches work naturally.
//
// Per phase: A-tile (32 rows x K) staged via the verified global_load_lds
// XOR-8 chunk swizzle; W fragments loaded direct global->VGPR (16 B/lane,
// L2-hot). kacc + h live in VGPRs across the whole kernel (row-local =>
// thread-local; mapping fixed by the L3 tile decomposition). MFMA K-order
// per output element identical to the verified R1 cores.
// Block: 512 thr (8 waves, 2/SIMD). LDS 64 KB. VGPR target <= 256.
// ===========================================================================

// L1: x1i = i8(tanh(x0b . W1^T + b1) * 127).  M=32, N=1024, K=512.
__device__ __forceinline__ void p1(const bf16* __restrict__ A, const bf16* __restrict__ W,
                                   const float* __restrict__ bias, int8_t* __restrict__ out,
                                   char* smem, int row0) {
    const int tid = threadIdx.x;
    const int lane = tid & 63, w = tid >> 6;
    const int quad = lane >> 4, l16 = lane & 15;
    const int x7 = l16 & 7;

    __syncthreads();   // prior phase's LDS reads done before overwrite
#pragma unroll
    for (int jj = 0; jj < 4; ++jj) {           // 2048 chunks: 32 rows x 64
        const int q = tid + jj * 512;
        const int r = q >> 6, p = q & 63, sg = p ^ (r & 7);
        load_lds16(A + (size_t)(row0 + r) * 512 + sg * 8, smem + q * 16);
    }
    __syncthreads();   // waitcnt(0) + barrier: staging complete

    floatx4 acc[2][8];
    const floatx4 zero = {0.f, 0.f, 0.f, 0.f};
#pragma unroll
    for (int mt = 0; mt < 2; ++mt)
#pragma unroll
        for (int nt = 0; nt < 8; ++nt) acc[mt][nt] = zero;

    const bf16* wp = W + (size_t)(w * 128 + l16) * 512 + quad * 8;
    for (int kt = 0; kt < 8; ++kt) {
#pragma unroll
        for (int kk = 0; kk < 2; ++kk) {
            short8 bfr[8];
#pragma unroll
            for (int nt = 0; nt < 8; ++nt)
                bfr[nt] = *(const short8*)(wp + nt * 8192 + kt * 64 + kk * 32);
            short8 af[2];
#pragma unroll
            for (int mt = 0; mt < 2; ++mt)
                af[mt] = *(const short8*)(smem + (mt * 16 + l16) * 1024 +
                                          ((kt * 8 + kk * 4 + quad) ^ x7) * 16);
#pragma unroll
            for (int mt = 0; mt < 2; ++mt)
#pragma unroll
                for (int nt = 0; nt < 8; ++nt)
                    acc[mt][nt] = __builtin_amdgcn_mfma_f32_16x16x32_bf16(
                        af[mt], bfr[nt], acc[mt][nt], 0, 0, 0);
        }
    }

    const int n0 = w * 128 + l16;
#pragma unroll
    for (int mt = 0; mt < 2; ++mt)
#pragma unroll
        for (int nt = 0; nt < 8; ++nt) {
            const int n = n0 + nt * 16;
            const float bb = bias[n];
#pragma unroll
            for (int i = 0; i < 4; ++i) {
                const int m = row0 + mt * 16 + quad * 4 + i;
                const float t = fast_tanh(acc[mt][nt][i] + bb);
                out[(size_t)m * 1024 + n] = (int8_t)__float2int_rn(t * 127.f);
            }
        }
}

// L2: x2b = bf16(tanh(acc*dq[n] + b2)), i8 core. M=32, N=1024, K=1024.
__device__ __forceinline__ void p2(const int8_t* __restrict__ A, const int8_t* __restrict__ W,
                                   const float* __restrict__ dq, const float* __restrict__ bias,
                                   bf16* __restrict__ out, char* smem, int row0) {
    const int tid = threadIdx.x;
    const int lane = tid & 63, w = tid >> 6;
    const int quad = lane >> 4, l16 = lane & 15;
    const int x7 = l16 & 7;

    __syncthreads();
#pragma unroll
    for (int jj = 0; jj < 4; ++jj) {           // 2048 chunks: 32 rows x 64
        const int q = tid + jj * 512;
        const int r = q >> 6, p = q & 63, sg = p ^ (r & 7);
        load_lds16(A + (size_t)(row0 + r) * 1024 + sg * 16, smem + q * 16);
    }
    __syncthreads();

    int4v acc[2][8];
    const int4v izero = {0, 0, 0, 0};
#pragma unroll
    for (int mt = 0; mt < 2; ++mt)
#pragma unroll
        for (int nt = 0; nt < 8; ++nt) acc[mt][nt] = izero;

    const int8_t* wp = W + (size_t)(w * 128 + l16) * 1024 + quad * 16;
    for (int kt = 0; kt < 8; ++kt) {
#pragma unroll
        for (int kk = 0; kk < 2; ++kk) {
            int4v bfr[8];
#pragma unroll
            for (int nt = 0; nt < 8; ++nt)
                bfr[nt] = *(const int4v*)(wp + nt * 16384 + kt * 128 + kk * 64);
            int4v af[2];
#pragma unroll
            for (int mt = 0; mt < 2; ++mt)
                af[mt] = *(const int4v*)(smem + (mt * 16 + l16) * 1024 +
                                         ((kt * 8 + kk * 4 + quad) ^ x7) * 16);
#pragma unroll
            for (int mt = 0; mt < 2; ++mt)
#pragma unroll
                for (int nt = 0; nt < 8; ++nt)
                    acc[mt][nt] = __builtin_amdgcn_mfma_i32_16x16x64_i8(
                        af[mt], bfr[nt], acc[mt][nt], 0, 0, 0);
        }
    }

    const int n0 = w * 128 + l16;
#pragma unroll
    for (int mt = 0; mt < 2; ++mt)
#pragma unroll
        for (int nt = 0; nt < 8; ++nt) {
            const int n = n0 + nt * 16;
            const float bb = bias[n];
            const float dqn = dq[n];
#pragma unroll
            for (int i = 0; i < 4; ++i) {
                const int m = row0 + mt * 16 + quad * 4 + i;
                out[(size_t)m * 1024 + n] =
                    __float2bfloat16(fast_tanh((float)acc[mt][nt][i] * dqn + bb));
            }
        }
}

__global__ void __launch_bounds__(512, 2)
ode_rows(const float* __restrict__ h_in, float* __restrict__ h_fin,
         const bf16* __restrict__ W1b, const float* __restrict__ b1,
         const int8_t* __restrict__ W2i, const float* __restrict__ dqv,
         const float* __restrict__ b2,
         const bf16* __restrict__ W3b, const float* __restrict__ b3,
         bf16* __restrict__ x0b, int8_t* __restrict__ x1i, bf16* __restrict__ x2b,
         const float* __restrict__ temb) {
    __shared__ alignas(16) char smem[65536];
    const int row0 = blockIdx.x * 32;          // 256 blocks x 32 rows
    const int tid = threadIdx.x;
    const int lane = tid & 63, w = tid >> 6;
    const int quad = lane >> 4, l16 = lane & 15;
    const int x7 = l16 & 7;
    const float dt = 0.1f;

    // Persistent per-thread RK4 state: 32 elements, fixed by the L3 tile map
    // element j=(mt*4+nt)*4+i: m = row0 + mt*16 + quad*4 + i, n = w*64 + nt*16 + l16
    float hreg[32], kacc[32];
#pragma unroll
    for (int mt = 0; mt < 2; ++mt)
#pragma unroll
        for (int nt = 0; nt < 4; ++nt)
#pragma unroll
            for (int i = 0; i < 4; ++i)
                hreg[(mt * 4 + nt) * 4 + i] =
                    h_in[(size_t)(row0 + mt * 16 + quad * 4 + i) * 512 +
                         (w * 64 + nt * 16 + l16)];
#pragma unroll
    for (int j = 0; j < 32; ++j) kacc[j] = 0.f;

    for (int s = 0; s < 10; ++s) {
        const float* tmid = temb + (size_t)(2 * s + 1) * 512;
        const float* tend = temb + (size_t)(2 * s + 2) * 512;
        for (int e = 0; e < 4; ++e) {
            p1(x0b, W1b, b1, x1i, smem, row0);
            p2(x1i, W2i, dqv, b2, x2b, smem, row0);

            // ---- L3: M=32, N=512, K=1024, A = x2b (64 KB LDS stage) ----
            __syncthreads();
#pragma unroll
            for (int jj = 0; jj < 8; ++jj) {   // 4096 chunks: 32 rows x 128
                const int q = tid + jj * 512;
                const int r = q >> 7, p = q & 127, sg = p ^ (r & 7);
                load_lds16(x2b + (size_t)(row0 + r) * 1024 + sg * 8, smem + q * 16);
            }
            __syncthreads();

            floatx4 acc[2][4];
            const floatx4 zero = {0.f, 0.f, 0.f, 0.f};
#pragma unroll
            for (int mt = 0; mt < 2; ++mt)
#pragma unroll
                for (int nt = 0; nt < 4; ++nt) acc[mt][nt] = zero;

            const bf16* wp = W3b + (size_t)(w * 64 + l16) * 1024 + quad * 8;
            for (int kt = 0; kt < 16; ++kt) {
#pragma unroll
                for (int kk = 0; kk < 2; ++kk) {
                    short8 bfr[4];
#pragma unroll
                    for (int nt = 0; nt < 4; ++nt)
                        bfr[nt] = *(const short8*)(wp + nt * 16384 + kt * 64 + kk * 32);
                    short8 af[2];
#pragma unroll
                    for (int mt = 0; mt < 2; ++mt)
                        af[mt] = *(const short8*)(smem + (mt * 16 + l16) * 2048 +
                                                  ((kt * 8 + kk * 4 + quad) ^ x7) * 16);
#pragma unroll
                    for (int mt = 0; mt < 2; ++mt)
#pragma unroll
                        for (int nt = 0; nt < 4; ++nt)
                            acc[mt][nt] = __builtin_amdgcn_mfma_f32_16x16x32_bf16(
                                af[mt], bfr[nt], acc[mt][nt], 0, 0, 0);
                }
            }

            // ---- RK4 epilogue (register-resident kacc/h) ----
            const float* te = (e <= 1) ? tmid : tend;
#pragma unroll
            for (int mt = 0; mt < 2; ++mt)
#pragma unroll
                for (int nt = 0; nt < 4; ++nt) {
                    const int n = w * 64 + nt * 16 + l16;
                    const float bb = b3[n];
                    const float tv = te[n];
#pragma unroll
                    for (int i = 0; i < 4; ++i) {
                        const int j = (mt * 4 + nt) * 4 + i;
                        const int m = row0 + mt * 16 + quad * 4 + i;
                        const size_t idx = (size_t)m * 512 + n;
                        const float kv = acc[mt][nt][i] + bb;
                        if (e == 0) {
                            kacc[j] = kv;
                            const float hbf = __bfloat162float(__float2bfloat16(hreg[j]));
                            x0b[idx] = __float2bfloat16(hbf + 0.05f * kv + tv);
                        } else if (e == 1) {
                            kacc[j] += 2.f * kv;
                            const float hbf = __bfloat162float(__float2bfloat16(hreg[j]));
                            x0b[idx] = __float2bfloat16(hbf + 0.05f * kv + tv);
                        } else if (e == 2) {
                            kacc[j] += 2.f * kv;
                            const float hbf = __bfloat162float(__float2bfloat16(hreg[j]));
                            x0b[idx] = __float2bfloat16(hbf + 0.1f * kv + tv);
                        } else {
                            const float hn = hreg[j] + (dt / 6.f) * (kacc[j] + kv);
                            hreg[j] = hn;
                            if (s == 9) h_fin[idx] = hn;
                            else        x0b[idx] = __float2bfloat16(hn + tv);
                        }
                    }
                }
        }
    }
}

// ===========================================================================
// Prep kernels.
// ===========================================================================

__global__ void f2b_kern(const float* __restrict__ src, bf16* __restrict__ dst, int n) {
    const int i = blockIdx.x * blockDim.x + threadIdx.x;
    if (i < n) dst[i] = __float2bfloat16(src[i]);
}

// Per-row i8 quantization of W2 (N=1024 rows, K=1024): row n scaled by
// 127/rowmax_n (clamped), dq[n] = rowmax_n/127^2 (includes x1's /127).
__global__ void quantW2_row(const float* __restrict__ W, int K,
                            int8_t* __restrict__ out, float* __restrict__ dq) {
    __shared__ float red[256];
    const int row = blockIdx.x, tid = threadIdx.x;
    const float* src = W + (size_t)row * K;
    float m = 0.f;
    for (int k = tid; k < K; k += 256) m = fmaxf(m, fabsf(src[k]));
    red[tid] = m;
    __syncthreads();
    for (int s = 128; s > 0; s >>= 1) {
        if (tid < s) red[tid] = fmaxf(red[tid], red[tid + s]);
        __syncthreads();
    }
    const float rmax = fmaxf(red[0], 1e-8f);
    const float sc = 127.f / rmax;
    int8_t* dst = out + (size_t)row * K;
    for (int k = tid; k < K; k += 256) {
        int v = __float2int_rn(src[k] * sc);
        v = v > 127 ? 127 : (v < -127 ? -127 : v);
        dst[k] = (int8_t)v;
    }
    if (tid == 0) dq[row] = rmax / (127.f * 127.f);
}

// temb[j][n] = (j*dt/2)*Wt[n] + bt[n], j = 0..20
__global__ void temb_kern(const float* __restrict__ Wt, const float* __restrict__ bt,
                          float* __restrict__ temb, float half_dt, int total) {
    const int i = blockIdx.x * blockDim.x + threadIdx.x;
    if (i < total) {
        const int j = i >> 9, n = i & 511;
        temb[i] = (j * half_dt) * Wt[n] + bt[n];
    }
}

__global__ void prep_kern(const float* __restrict__ h, const float* __restrict__ temb0,
                          bf16* __restrict__ x0, int total) {
    const int i = blockIdx.x * blockDim.x + threadIdx.x;
    if (i < total) x0[i] = __float2bfloat16(h[i] + temb0[i & 511]);
}

extern "C" void kernel_launch(void* const* d_in, const int* in_sizes, int n_in,
                              void* d_out, int out_size, void* d_ws, size_t ws_size,
                              hipStream_t stream) {
    const float* h_in = (const float*)d_in[0];
    const float* W1 = (const float*)d_in[1];
    const float* b1 = (const float*)d_in[2];
    const float* W2 = (const float*)d_in[3];
    const float* b2 = (const float*)d_in[4];
    const float* W3 = (const float*)d_in[5];
    const float* b3 = (const float*)d_in[6];
    const float* Wt = (const float*)d_in[7];
    const float* bt = (const float*)d_in[8];
    const int B = 8192, H = 512, H2 = 1024;
    const float dt = 0.1f;

    char* ws = (char*)d_ws;
    auto alloc = [&](size_t bytes) {
        char* p = ws;
        ws += (bytes + 255) & ~(size_t)255;
        return p;
    };
    bf16* W1b = (bf16*)alloc((size_t)H2 * H * 2);
    int8_t* W2i = (int8_t*)alloc((size_t)H2 * H2);      // i8, per-row scaled
    float* dqv  = (float*)alloc((size_t)H2 * 4);        // per-row dequant
    bf16* W3b = (bf16*)alloc((size_t)H * H2 * 2);
    bf16* x0b = (bf16*)alloc((size_t)B * H * 2);
    int8_t* x1i = (int8_t*)alloc((size_t)B * H2);       // i8 tanh outputs *127
    bf16* x2b = (bf16*)alloc((size_t)B * H2 * 2);
    float* temb = (float*)alloc((size_t)21 * H * 4);
    float* h_fin = (float*)d_out;   // final h (fp32), written once at s==9

    {
        int n = H2 * H;
        f2b_kern<<<(n + 255) / 256, 256, 0, stream>>>(W1, W1b, n);
        quantW2_row<<<H2, 256, 0, stream>>>(W2, H2, W2i, dqv);
        n = H * H2;
        f2b_kern<<<(n + 255) / 256, 256, 0, stream>>>(W3, W3b, n);
    }
    {
        const int total = 21 * H;
        temb_kern<<<(total + 255) / 256, 256, 0, stream>>>(Wt, bt, temb, dt * 0.5f, total);
    }
    {
        const int total = B * H;
        prep_kern<<<(total + 255) / 256, 256, 0, stream>>>(h_in, temb, x0b, total);
    }

    // One plain launch: 256 blocks (1/CU) x 512 threads, zero grid syncs.
    ode_rows<<<dim3(256), dim3(512), 0, stream>>>(
        h_in, h_fin, W1b, b1, W2i, dqv, b2, W3b, b3,
        x0b, x1i, x2b, temb);
}